// Round 1
// baseline (275.816 us; speedup 1.0000x reference)
//
#include <hip/hip_runtime.h>
#include <stdint.h>

#define DEVINL __device__ __forceinline__

typedef __attribute__((ext_vector_type(8))) __bf16 bf16x8;
typedef __attribute__((ext_vector_type(4))) float f32x4;

// ---------- helpers ----------
DEVINL unsigned short f2bf(float f) {
  union { float f; unsigned int u; } v; v.f = f;
  unsigned int u = v.u;
  unsigned int r = (u + 0x7fffu + ((u >> 16) & 1u)) >> 16;  // RNE
  return (unsigned short)r;
}

DEVINL float sigmoid_fast(float x) { return 1.f / (1.f + __expf(-x)); }

DEVINL float tanh_fast(float x) {
  x = fminf(15.f, fmaxf(-15.f, x));
  float e = __expf(2.f * x);
  return (e - 1.f) / (e + 1.f);
}

// async global->LDS 16B per lane; lds base must be wave-uniform, HW scatters lane i to base+i*16
#define GLD_LDS16(gptr, lptr)                                                  \
  __builtin_amdgcn_global_load_lds(                                            \
      (__attribute__((address_space(1))) void*)(gptr),                         \
      (__attribute__((address_space(3))) void*)(lptr), 16, 0, 0)

// ---------- prep: concat(obs, act) -> bf16 [B,544] ----------
__global__ void prep_input(const float* __restrict__ obs,
                           const float* __restrict__ act,
                           unsigned short* __restrict__ A0) {
  const int total = 32768 * 68;  // 16B chunks (8 bf16) per row: 68
  for (int c = blockIdx.x * blockDim.x + threadIdx.x; c < total;
       c += gridDim.x * blockDim.x) {
    const int b = c / 68, c8 = c % 68;
    const float* src = (c8 < 64) ? (obs + (size_t)b * 512 + c8 * 8)
                                 : (act + (size_t)b * 32 + (c8 - 64) * 8);
    float4 f0 = *(const float4*)src;
    float4 f1 = *(const float4*)(src + 4);
    unsigned short u[8] = {f2bf(f0.x), f2bf(f0.y), f2bf(f0.z), f2bf(f0.w),
                           f2bf(f1.x), f2bf(f1.y), f2bf(f1.z), f2bf(f1.w)};
    *(uint4*)(A0 + (size_t)b * 544 + c8 * 8) = *(uint4*)u;
  }
}

// ---------- prep: fp32 -> bf16 generic ----------
__global__ void cvt_bf16(const float* __restrict__ src,
                         unsigned short* __restrict__ dst, int n4) {
  for (int i = blockIdx.x * blockDim.x + threadIdx.x; i < n4;
       i += gridDim.x * blockDim.x) {
    float4 f = *(const float4*)(src + (size_t)i * 4);
    unsigned short u[4] = {f2bf(f.x), f2bf(f.y), f2bf(f.z), f2bf(f.w)};
    *(uint2*)(dst + (size_t)i * 4) = *(uint2*)u;
  }
}

// ---------- prep: hvec[j] = dot(W_hh[j,:], hid) + b_hh[j] + b_ih[j] ----------
__global__ void calc_hvec(const float* __restrict__ Whh,
                          const float* __restrict__ hid,
                          const float* __restrict__ bhh,
                          const float* __restrict__ bih,
                          float* __restrict__ hvec) {
  const int j = blockIdx.x * 4 + (threadIdx.x >> 6);
  const int lane = threadIdx.x & 63;
  const float* w = Whh + (size_t)j * 512;
  float s = 0.f;
  for (int k = lane; k < 512; k += 64) s += w[k] * hid[k];
  for (int off = 32; off; off >>= 1) s += __shfl_down(s, off, 64);
  if (lane == 0) hvec[j] = s + bhh[j] + bih[j];
}

// ---------- GEMM1: X = relu(A0 @ W1^T + b1), bf16 out ----------
__global__ __launch_bounds__(256, 2) void gemm1_relu(
    const unsigned short* __restrict__ A0,   // [32768,544] bf16
    const unsigned short* __restrict__ W1b,  // [512,544] bf16
    const float* __restrict__ b1,            // [512]
    unsigned short* __restrict__ X) {        // [32768,512] bf16
  constexpr int KT = 17, LD = 544;
  __shared__ __align__(16) unsigned short As[128 * 32];
  __shared__ __align__(16) unsigned short Bs[128 * 32];
  const int tid = threadIdx.x, wave = tid >> 6, lane = tid & 63;
  const int m0 = blockIdx.x * 128, n0 = blockIdx.y * 128;
  const int wr = (wave >> 1) * 64, wc = (wave & 1) * 64;
  f32x4 acc[4][4] = {};

  const int c0 = tid, c1 = tid + 256;  // chunk: row=c>>2, col8=c&3
  for (int kt = 0; kt < KT; ++kt) {
    const int k0 = kt * 32;
    GLD_LDS16(A0 + (size_t)(m0 + (c0 >> 2)) * LD + k0 + (c0 & 3) * 8, &As[wave * 512]);
    GLD_LDS16(A0 + (size_t)(m0 + (c1 >> 2)) * LD + k0 + (c1 & 3) * 8, &As[2048 + wave * 512]);
    GLD_LDS16(W1b + (size_t)(n0 + (c0 >> 2)) * LD + k0 + (c0 & 3) * 8, &Bs[wave * 512]);
    GLD_LDS16(W1b + (size_t)(n0 + (c1 >> 2)) * LD + k0 + (c1 & 3) * 8, &Bs[2048 + wave * 512]);
    asm volatile("s_waitcnt vmcnt(0)" ::: "memory");
    __syncthreads();
    const int fr = lane & 15, kq = (lane >> 4) * 8;
    bf16x8 a[4], b[4];
#pragma unroll
    for (int i = 0; i < 4; ++i) a[i] = *(const bf16x8*)&As[(wr + i * 16 + fr) * 32 + kq];
#pragma unroll
    for (int j = 0; j < 4; ++j) b[j] = *(const bf16x8*)&Bs[(wc + j * 16 + fr) * 32 + kq];
#pragma unroll
    for (int i = 0; i < 4; ++i)
#pragma unroll
      for (int j = 0; j < 4; ++j)
        acc[i][j] = __builtin_amdgcn_mfma_f32_16x16x32_bf16(a[i], b[j], acc[i][j], 0, 0, 0);
    __syncthreads();
  }
  const int rbase = (lane >> 4) * 4, cn = lane & 15;
#pragma unroll
  for (int i = 0; i < 4; ++i)
#pragma unroll
    for (int j = 0; j < 4; ++j) {
      const int gn = n0 + wc + j * 16 + cn;
      const float bias = b1[gn];
#pragma unroll
      for (int r = 0; r < 4; ++r) {
        const int gm = m0 + wr + i * 16 + rbase + r;
        float v = acc[i][j][r] + bias;
        v = v > 0.f ? v : 0.f;
        X[(size_t)gm * 512 + gn] = f2bf(v);
      }
    }
}

// ---------- GEMM2 (4 gate quadrants) + LSTM epilogue ----------
__global__ __launch_bounds__(256, 2) void gemm2_lstm(
    const unsigned short* __restrict__ X,    // [32768,512] bf16
    const unsigned short* __restrict__ Wih,  // [2048,512] bf16
    const float* __restrict__ hvec,          // [2048]
    const float* __restrict__ cell,          // [512]
    unsigned short* __restrict__ H,          // [32768,512] bf16 out
    float* __restrict__ hlast,               // [512] fp32 out
    float* __restrict__ clast) {             // [512] fp32 out
  constexpr int KT = 16;
  __shared__ __align__(16) unsigned short As[128 * 32];
  __shared__ __align__(16) unsigned short Bs[4 * 32 * 32];
  const int tid = threadIdx.x, wave = tid >> 6, lane = tid & 63;
  const int m0 = blockIdx.x * 128;
  const int n0 = blockIdx.y * 32;            // quadrant-column tile
  const int wr = (wave >> 1) * 64, wc = (wave & 1) * 16;
  f32x4 acc[4][4] = {};                      // [row-tile][quadrant]

  const int c0 = tid, c1 = tid + 256;
  for (int kt = 0; kt < KT; ++kt) {
    const int k0 = kt * 32;
    // A tile [128,32]: chunk c -> row=c>>2, col8=c&3
    GLD_LDS16(X + (size_t)(m0 + (c0 >> 2)) * 512 + k0 + (c0 & 3) * 8, &As[wave * 512]);
    GLD_LDS16(X + (size_t)(m0 + (c1 >> 2)) * 512 + k0 + (c1 & 3) * 8, &As[2048 + wave * 512]);
    // B tiles [4][32,32]: chunk c -> q=c>>7, row=(c>>2)&31, col8=c&3
    GLD_LDS16(Wih + (size_t)((c0 >> 7) * 512 + n0 + ((c0 >> 2) & 31)) * 512 + k0 + (c0 & 3) * 8,
              &Bs[wave * 512]);
    GLD_LDS16(Wih + (size_t)((c1 >> 7) * 512 + n0 + ((c1 >> 2) & 31)) * 512 + k0 + (c1 & 3) * 8,
              &Bs[2048 + wave * 512]);
    asm volatile("s_waitcnt vmcnt(0)" ::: "memory");
    __syncthreads();
    const int fr = lane & 15, kq = (lane >> 4) * 8;
    bf16x8 a[4], b[4];
#pragma unroll
    for (int i = 0; i < 4; ++i) a[i] = *(const bf16x8*)&As[(wr + i * 16 + fr) * 32 + kq];
#pragma unroll
    for (int q = 0; q < 4; ++q) b[q] = *(const bf16x8*)&Bs[q * 1024 + (wc + fr) * 32 + kq];
#pragma unroll
    for (int i = 0; i < 4; ++i)
#pragma unroll
      for (int q = 0; q < 4; ++q)
        acc[i][q] = __builtin_amdgcn_mfma_f32_16x16x32_bf16(a[i], b[q], acc[i][q], 0, 0, 0);
    __syncthreads();
  }
  const int rbase = (lane >> 4) * 4, cn = lane & 15;
  const int gn = n0 + wc + cn;  // column in [0,512)
  const float hv_i = hvec[gn];
  const float hv_f = hvec[gn + 512];
  const float hv_g = hvec[gn + 1024];
  const float hv_o = hvec[gn + 1536];
  const float cprev = cell[gn];
#pragma unroll
  for (int i = 0; i < 4; ++i)
#pragma unroll
    for (int r = 0; r < 4; ++r) {
      const int gm = m0 + wr + i * 16 + rbase + r;
      float si = sigmoid_fast(acc[i][0][r] + hv_i);
      float sf = sigmoid_fast(acc[i][1][r] + hv_f);
      float tg = tanh_fast(acc[i][2][r] + hv_g);
      float so = sigmoid_fast(acc[i][3][r] + hv_o);
      float cnew = sf * cprev + si * tg;
      float hnew = so * tanh_fast(cnew);
      H[(size_t)gm * 512 + gn] = f2bf(hnew);
      if (gm == 32767) { hlast[gn] = hnew; clast[gn] = cnew; }
    }
}

// ---------- GEMM3: Q = H @ W2^T + b2 (W2 fully LDS-resident) ----------
__global__ __launch_bounds__(256, 2) void gemm3(
    const unsigned short* __restrict__ H,    // [32768,512] bf16
    const unsigned short* __restrict__ W2b,  // [32,512] bf16
    const float* __restrict__ b2,            // [32]
    float* __restrict__ Q) {                 // [32768,32] fp32
  constexpr int KT = 16, LDW = 520;          // padded stride: banks spread, 2-way only
  __shared__ __align__(16) unsigned short As[128 * 32];
  __shared__ __align__(16) unsigned short Ws[32 * LDW];
  const int tid = threadIdx.x, wave = tid >> 6, lane = tid & 63;
  const int m0 = blockIdx.x * 128;
  // preload W2: 2048 16B-chunks
  for (int c = tid; c < 2048; c += 256) {
    const int row = c >> 6, col8 = c & 63;
    uint4 v = *(const uint4*)(W2b + row * 512 + col8 * 8);
    *(uint4*)&Ws[row * LDW + col8 * 8] = v;
  }
  f32x4 acc[2][2] = {};
  const int c0 = tid, c1 = tid + 256;
  for (int kt = 0; kt < KT; ++kt) {
    const int k0 = kt * 32;
    GLD_LDS16(H + (size_t)(m0 + (c0 >> 2)) * 512 + k0 + (c0 & 3) * 8, &As[wave * 512]);
    GLD_LDS16(H + (size_t)(m0 + (c1 >> 2)) * 512 + k0 + (c1 & 3) * 8, &As[2048 + wave * 512]);
    asm volatile("s_waitcnt vmcnt(0)" ::: "memory");
    __syncthreads();
    const int fr = lane & 15, kq = (lane >> 4) * 8;
    bf16x8 a[2], b[2];
#pragma unroll
    for (int i = 0; i < 2; ++i)
      a[i] = *(const bf16x8*)&As[(wave * 32 + i * 16 + fr) * 32 + kq];
#pragma unroll
    for (int j = 0; j < 2; ++j)
      b[j] = *(const bf16x8*)&Ws[(j * 16 + fr) * LDW + k0 + kq];
#pragma unroll
    for (int i = 0; i < 2; ++i)
#pragma unroll
      for (int j = 0; j < 2; ++j)
        acc[i][j] = __builtin_amdgcn_mfma_f32_16x16x32_bf16(a[i], b[j], acc[i][j], 0, 0, 0);
    __syncthreads();
  }
  const int rbase = (lane >> 4) * 4, cn = lane & 15;
#pragma unroll
  for (int i = 0; i < 2; ++i)
#pragma unroll
    for (int j = 0; j < 2; ++j) {
      const int gn = j * 16 + cn;
      const float bias = b2[gn];
#pragma unroll
      for (int r = 0; r < 4; ++r) {
        const int gm = m0 + wave * 32 + i * 16 + rbase + r;
        Q[(size_t)gm * 32 + gn] = acc[i][j][r] + bias;
      }
    }
}

// ---------- launch ----------
extern "C" void kernel_launch(void* const* d_in, const int* in_sizes, int n_in,
                              void* d_out, int out_size, void* d_ws, size_t ws_size,
                              hipStream_t stream) {
  const float* obs  = (const float*)d_in[0];
  const float* act  = (const float*)d_in[1];
  const float* hid  = (const float*)d_in[2];
  const float* cell = (const float*)d_in[3];
  const float* W1   = (const float*)d_in[4];
  const float* b1   = (const float*)d_in[5];
  const float* Wih  = (const float*)d_in[6];
  const float* bih  = (const float*)d_in[7];
  const float* Whh  = (const float*)d_in[8];
  const float* bhh  = (const float*)d_in[9];
  const float* W2   = (const float*)d_in[10];
  const float* b2   = (const float*)d_in[11];
  float* out = (float*)d_out;

  char* ws = (char*)d_ws;
  unsigned short* A0   = (unsigned short*)(ws);              // 35,651,584 B  [B,544] bf16
  unsigned short* H    = (unsigned short*)(ws);              // alias A0 (A0 dead after gemm1)
  unsigned short* X    = (unsigned short*)(ws + 35651584);   // 33,554,432 B  [B,512] bf16
  unsigned short* W1b  = (unsigned short*)(ws + 69206016);   //    557,056 B
  unsigned short* Wihb = (unsigned short*)(ws + 69763072);   //  2,097,152 B
  unsigned short* W2b  = (unsigned short*)(ws + 71860224);   //     32,768 B
  float*          hvec = (float*)(ws + 71892992);            //      8,192 B

  prep_input<<<2176, 256, 0, stream>>>(obs, act, A0);
  cvt_bf16<<<272, 256, 0, stream>>>(W1, W1b, 512 * 544 / 4);
  cvt_bf16<<<1024, 256, 0, stream>>>(Wih, Wihb, 2048 * 512 / 4);
  cvt_bf16<<<16, 256, 0, stream>>>(W2, W2b, 32 * 512 / 4);
  calc_hvec<<<512, 256, 0, stream>>>(Whh, hid, bhh, bih, hvec);

  gemm1_relu<<<dim3(256, 4), 256, 0, stream>>>(A0, W1b, b1, X);
  gemm2_lstm<<<dim3(256, 16), 256, 0, stream>>>(X, Wihb, hvec, cell, H,
                                                out + 32768 * 32,
                                                out + 32768 * 32 + 512);
  gemm3<<<256, 256, 0, stream>>>(H, W2b, b2, out);
}